// Round 7
// baseline (295.813 us; speedup 1.0000x reference)
//
#include <hip/hip_runtime.h>
#include <hip/hip_bf16.h>

typedef float nt4 __attribute__((ext_vector_type(4)));

constexpr int Bc  = 2;
constexpr int Nc  = 256;
constexpr int Dc  = 256;
constexpr int DHc = 256;

// ---- prep: K,V = x@W + b;  G = scale*K@Wq^T;  cc = scale*<bq,K_row>; also x->out ----
__global__ __launch_bounds__(256)
void prep_gvc(const float* __restrict__ x,
              const float* __restrict__ Wq, const float* __restrict__ bq,
              const float* __restrict__ Wk, const float* __restrict__ bk,
              const float* __restrict__ Wv, const float* __restrict__ bv,
              float* __restrict__ G, float* __restrict__ V, float* __restrict__ cc,
              float* __restrict__ xout) {
    constexpr int RPB = 4;
    constexpr float scale = 0.0625f;    // 1/sqrt(DH)
    __shared__ float xs[RPB][Dc];
    __shared__ float ks[RPB][DHc];
    const int r0 = blockIdx.x * RPB;
    const int dd = threadIdx.x;

    #pragma unroll
    for (int rr = 0; rr < RPB; ++rr) {
        float xv = x[(size_t)(r0 + rr) * Dc + dd];
        xs[rr][dd] = xv;
        xout[(size_t)(r0 + rr) * Dc + dd] = xv;   // passthrough output 0
    }
    __syncthreads();

    float ka[RPB], va[RPB];
    {
        float bkv = bk[dd], bvv = bv[dd];
        #pragma unroll
        for (int rr = 0; rr < RPB; ++rr) { ka[rr] = bkv; va[rr] = bvv; }
    }
    #pragma unroll 4
    for (int d0 = 0; d0 < Dc; ++d0) {
        float wk = Wk[(size_t)d0 * DHc + dd];
        float wv = Wv[(size_t)d0 * DHc + dd];
        #pragma unroll
        for (int rr = 0; rr < RPB; ++rr) {
            ka[rr] += xs[rr][d0] * wk;
            va[rr] += xs[rr][d0] * wv;
        }
    }
    #pragma unroll
    for (int rr = 0; rr < RPB; ++rr) {
        ks[rr][dd] = ka[rr];
        V[(size_t)(r0 + rr) * DHc + dd] = va[rr];
    }
    __syncthreads();

    float ga[RPB] = {};
    #pragma unroll 8
    for (int h = 0; h < DHc; ++h) {
        float wq = Wq[(size_t)dd * DHc + h];
        #pragma unroll
        for (int rr = 0; rr < RPB; ++rr) ga[rr] += ks[rr][h] * wq;
    }
    #pragma unroll
    for (int rr = 0; rr < RPB; ++rr)
        G[(size_t)(r0 + rr) * Dc + dd] = ga[rr] * scale;

    {
        int rr = dd >> 6, l = dd & 63;
        float p = 0.f;
        #pragma unroll
        for (int k = 0; k < 4; ++k) p += ks[rr][l + 64 * k] * bq[l + 64 * k];
        #pragma unroll
        for (int m = 1; m < 64; m <<= 1) p += __shfl_xor(p, m, 64);
        if (l == 0) cc[r0 + rr] = p * scale;
    }
}

// ---- main: linear copy-style streaming; 1 row per wave-iteration ----
// wave W -> (b, j, segment s); rows i = s*32 + t, t=0..31, fully unrolled.
// Per iteration: 3 linear 1KB wave-loads (e,G_i,V_i) + 1 linear 1KB NT store.
// All 32 iterations' loads are independent -> compiler pipelines to VGPR cap.
__global__ __launch_bounds__(256, 4)
void edge_main(const float* __restrict__ e,
               const float* __restrict__ G,
               const float* __restrict__ V,
               const float* __restrict__ cc,
               float* __restrict__ eout) {
    const int W = blockIdx.x * 4 + (threadIdx.x >> 6);   // wave id, 0..4095
    const int l = threadIdx.x & 63;
    const int b   = W >> 11;
    const int rem = W & 2047;
    const int j   = rem >> 3;
    const int s   = rem & 7;
    const int i0  = s * 32;

    const size_t nb = (size_t)b * Nc;
    const float4* G4 = reinterpret_cast<const float4*>(G);
    const float4* V4 = reinterpret_cast<const float4*>(V);

    const float4 gj = G4[(nb + j) * 64 + l];
    const float4 vj = V4[(nb + j) * 64 + l];
    const float  cj = cc[nb + j];

    const float4* e4 = reinterpret_cast<const float4*>(e) +
                       (((size_t)b * Nc + j) * Nc + i0) * 64 + l;
    float4* o4 = reinterpret_cast<float4*>(eout) +
                 (((size_t)b * Nc + j) * Nc + i0) * 64 + l;
    const float4* Gi = G4 + (nb + i0) * 64 + l;
    const float4* Vi = V4 + (nb + i0) * 64 + l;
    const float*  ccp = cc + nb + i0;

    float4 ev = e4[0], gi = Gi[0], vi = Vi[0];
    float  ci = ccp[0];

    #pragma unroll
    for (int t = 0; t < 32; ++t) {
        float4 nev, ngi, nvi;
        float  nci;
        if (t < 31) {
            nev = e4[(size_t)(t + 1) * 64];
            ngi = Gi[(size_t)(t + 1) * 64];
            nvi = Vi[(size_t)(t + 1) * 64];
            nci = ccp[t + 1];
        }
        float si = ev.x * gi.x + ev.y * gi.y + ev.z * gi.z + ev.w * gi.w;
        float sj = ev.x * gj.x + ev.y * gj.y + ev.z * gj.z + ev.w * gj.w;
        #pragma unroll
        for (int m = 1; m < 64; m <<= 1) {
            si += __shfl_xor(si, m, 64);
            sj += __shfl_xor(sj, m, 64);
        }
        si += ci;
        sj += cj;
        const float ai = 1.f / (1.f + __expf(sj - si));  // scores pre-scaled by 1/16
        const float aj = 1.f - ai;

        nt4 o;
        o.x = ai * vi.x + aj * vj.x;
        o.y = ai * vi.y + aj * vj.y;
        o.z = ai * vi.z + aj * vj.z;
        o.w = ai * vi.w + aj * vj.w;
        __builtin_nontemporal_store(o, reinterpret_cast<nt4*>(&o4[(size_t)t * 64]));

        ev = nev; gi = ngi; vi = nvi; ci = nci;
    }
}

extern "C" void kernel_launch(void* const* d_in, const int* in_sizes, int n_in,
                              void* d_out, int out_size, void* d_ws, size_t ws_size,
                              hipStream_t stream) {
    const float* x  = (const float*)d_in[0];
    const float* e  = (const float*)d_in[1];
    const float* Wq = (const float*)d_in[2];
    const float* bq = (const float*)d_in[3];
    const float* Wk = (const float*)d_in[4];
    const float* bk = (const float*)d_in[5];
    const float* Wv = (const float*)d_in[6];
    const float* bv = (const float*)d_in[7];
    float* out = (float*)d_out;

    float* G  = (float*)d_ws;                       // [B*N, D]
    float* V  = G + (size_t)Bc * Nc * Dc;           // [B*N, DH]
    float* cc = V + (size_t)Bc * Nc * DHc;          // [B*N]

    prep_gvc<<<Bc * Nc / 4, 256, 0, stream>>>(x, Wq, bq, Wk, bk, Wv, bv,
                                              G, V, cc, out);
    edge_main<<<Bc * Nc * 8 / 4, 256, 0, stream>>>(
        e, G, V, cc, out + (size_t)Bc * Nc * Dc);
}

// Round 8
// 291.037 us; speedup vs baseline: 1.0164x; 1.0164x over previous
//
#include <hip/hip_runtime.h>
#include <hip/hip_bf16.h>

typedef float nt4 __attribute__((ext_vector_type(4)));

constexpr int Bc  = 2;
constexpr int Nc  = 256;
constexpr int Dc  = 256;
constexpr int DHc = 256;

// 16-lane sum via DPP (VALU-only, no LDS): quad_perm[1,0,3,2], quad_perm[2,3,0,1],
// row_half_mirror, row_mirror. All 16 lanes end with the group sum.
__device__ __forceinline__ float dpp_sum16(float v) {
    float t;
    t = __int_as_float(__builtin_amdgcn_mov_dpp(__float_as_int(v), 0xB1, 0xF, 0xF, true)); v += t;
    t = __int_as_float(__builtin_amdgcn_mov_dpp(__float_as_int(v), 0x4E, 0xF, 0xF, true)); v += t;
    t = __int_as_float(__builtin_amdgcn_mov_dpp(__float_as_int(v), 0x141, 0xF, 0xF, true)); v += t;
    t = __int_as_float(__builtin_amdgcn_mov_dpp(__float_as_int(v), 0x140, 0xF, 0xF, true)); v += t;
    return v;
}

// ---- prep: K,V = x@W + b;  G = scale*K@Wq^T;  cc = scale*<bq,K_row>; also x->out ----
__global__ __launch_bounds__(256)
void prep_gvc(const float* __restrict__ x,
              const float* __restrict__ Wq, const float* __restrict__ bq,
              const float* __restrict__ Wk, const float* __restrict__ bk,
              const float* __restrict__ Wv, const float* __restrict__ bv,
              float* __restrict__ G, float* __restrict__ V, float* __restrict__ cc,
              float* __restrict__ xout) {
    constexpr int RPB = 4;
    constexpr float scale = 0.0625f;    // 1/sqrt(DH)
    __shared__ float xs[RPB][Dc];
    __shared__ float ks[RPB][DHc];
    const int r0 = blockIdx.x * RPB;
    const int dd = threadIdx.x;

    #pragma unroll
    for (int rr = 0; rr < RPB; ++rr) {
        float xv = x[(size_t)(r0 + rr) * Dc + dd];
        xs[rr][dd] = xv;
        xout[(size_t)(r0 + rr) * Dc + dd] = xv;   // passthrough output 0
    }
    __syncthreads();

    float ka[RPB], va[RPB];
    {
        float bkv = bk[dd], bvv = bv[dd];
        #pragma unroll
        for (int rr = 0; rr < RPB; ++rr) { ka[rr] = bkv; va[rr] = bvv; }
    }
    #pragma unroll 4
    for (int d0 = 0; d0 < Dc; ++d0) {
        float wk = Wk[(size_t)d0 * DHc + dd];
        float wv = Wv[(size_t)d0 * DHc + dd];
        #pragma unroll
        for (int rr = 0; rr < RPB; ++rr) {
            ka[rr] += xs[rr][d0] * wk;
            va[rr] += xs[rr][d0] * wv;
        }
    }
    #pragma unroll
    for (int rr = 0; rr < RPB; ++rr) {
        ks[rr][dd] = ka[rr];
        V[(size_t)(r0 + rr) * DHc + dd] = va[rr];
    }
    __syncthreads();

    float ga[RPB] = {};
    #pragma unroll 8
    for (int h = 0; h < DHc; ++h) {
        float wq = Wq[(size_t)dd * DHc + h];
        #pragma unroll
        for (int rr = 0; rr < RPB; ++rr) ga[rr] += ks[rr][h] * wq;
    }
    #pragma unroll
    for (int rr = 0; rr < RPB; ++rr)
        G[(size_t)(r0 + rr) * Dc + dd] = ga[rr] * scale;

    {
        int rr = dd >> 6, l = dd & 63;
        float p = 0.f;
        #pragma unroll
        for (int k = 0; k < 4; ++k) p += ks[rr][l + 64 * k] * bq[l + 64 * k];
        #pragma unroll
        for (int m = 1; m < 64; m <<= 1) p += __shfl_xor(p, m, 64);
        if (l == 0) cc[r0 + rr] = p * scale;
    }
}

// ---- pass A: scores only. wave -> (b, j, 16-row segment); 16-lane groups,
// 4 rows per unrolled iter; DPP reduce; writes ai (1 float/edge). ----
__global__ __launch_bounds__(256)
void score_pass(const float* __restrict__ e,
                const float* __restrict__ G,
                const float* __restrict__ cc,
                float* __restrict__ ai_out) {
    const int W = blockIdx.x * 4 + (threadIdx.x >> 6);   // 0..8191
    const int l = threadIdx.x & 63;
    const int b   = W >> 12;
    const int rem = W & 4095;
    const int j   = rem >> 4;
    const int seg = rem & 15;
    const int g   = l >> 4;
    const int c4  = l & 15;
    const int r0  = seg * 16;

    const size_t nb = (size_t)b * Nc;
    const float4* G4 = reinterpret_cast<const float4*>(G);

    const float4 gj0 = G4[(nb + j) * 64 + c4];
    const float4 gj1 = G4[(nb + j) * 64 + c4 + 16];
    const float4 gj2 = G4[(nb + j) * 64 + c4 + 32];
    const float4 gj3 = G4[(nb + j) * 64 + c4 + 48];
    const float  cj  = cc[nb + j];

    const float4* e4  = reinterpret_cast<const float4*>(e) +
                        (((size_t)b * Nc + j) * Nc + r0) * 64;
    const float4* Gi  = G4 + (nb + r0) * 64;
    const float*  ccp = cc + nb + r0;
    float* aout = ai_out + ((size_t)b * Nc + j) * Nc + r0;

    #pragma unroll
    for (int t = 0; t < 4; ++t) {
        const int r = t * 4 + g;
        const float ci = ccp[r];                         // early, off-chain
        float4 ev0 = e4[(size_t)r * 64 + c4];
        float4 ev1 = e4[(size_t)r * 64 + c4 + 16];
        float4 ev2 = e4[(size_t)r * 64 + c4 + 32];
        float4 ev3 = e4[(size_t)r * 64 + c4 + 48];
        float4 gi0 = Gi[(size_t)r * 64 + c4];
        float4 gi1 = Gi[(size_t)r * 64 + c4 + 16];
        float4 gi2 = Gi[(size_t)r * 64 + c4 + 32];
        float4 gi3 = Gi[(size_t)r * 64 + c4 + 48];

        float si, sj;
        si  = ev0.x * gi0.x + ev0.y * gi0.y + ev0.z * gi0.z + ev0.w * gi0.w;
        si += ev1.x * gi1.x + ev1.y * gi1.y + ev1.z * gi1.z + ev1.w * gi1.w;
        si += ev2.x * gi2.x + ev2.y * gi2.y + ev2.z * gi2.z + ev2.w * gi2.w;
        si += ev3.x * gi3.x + ev3.y * gi3.y + ev3.z * gi3.z + ev3.w * gi3.w;
        sj  = ev0.x * gj0.x + ev0.y * gj0.y + ev0.z * gj0.z + ev0.w * gj0.w;
        sj += ev1.x * gj1.x + ev1.y * gj1.y + ev1.z * gj1.z + ev1.w * gj1.w;
        sj += ev2.x * gj2.x + ev2.y * gj2.y + ev2.z * gj2.z + ev2.w * gj2.w;
        sj += ev3.x * gj3.x + ev3.y * gj3.y + ev3.z * gj3.z + ev3.w * gj3.w;

        si = dpp_sum16(si) + ci;
        sj = dpp_sum16(sj) + cj;
        const float ai = 1.f / (1.f + __expf(sj - si));  // scores pre-scaled by 1/16
        if (c4 == 0) aout[r] = ai;                       // lanes 0,16,32,48: 16B segment
    }
}

// ---- pass B: combine. wave -> (b, j, 16-row segment); per row:
// readlane(ai) broadcast, V_i from L2, 1KB linear NT store. ----
__global__ __launch_bounds__(256)
void combine_pass(const float* __restrict__ ai_in,
                  const float* __restrict__ V,
                  float* __restrict__ eout) {
    const int W = blockIdx.x * 4 + (threadIdx.x >> 6);   // 0..8191
    const int l = threadIdx.x & 63;
    const int b   = W >> 12;
    const int rem = W & 4095;
    const int j   = rem >> 4;
    const int seg = rem & 15;
    const int r0  = seg * 16;

    const size_t nb = (size_t)b * Nc;
    const float4* V4 = reinterpret_cast<const float4*>(V);
    const float4 vj = V4[(nb + j) * 64 + l];
    const float  av = ai_in[((size_t)b * Nc + j) * Nc + r0 + (l & 15)];

    const float4* Vi = V4 + (nb + r0) * 64 + l;
    float4* o4 = reinterpret_cast<float4*>(eout) +
                 (((size_t)b * Nc + j) * Nc + r0) * 64 + l;

    #pragma unroll
    for (int t = 0; t < 16; ++t) {
        const float ai = __int_as_float(
            __builtin_amdgcn_readlane(__float_as_int(av), t));
        const float aj = 1.f - ai;
        const float4 vi = Vi[(size_t)t * 64];
        nt4 o;
        o.x = ai * vi.x + aj * vj.x;
        o.y = ai * vi.y + aj * vj.y;
        o.z = ai * vi.z + aj * vj.z;
        o.w = ai * vi.w + aj * vj.w;
        __builtin_nontemporal_store(o, reinterpret_cast<nt4*>(&o4[(size_t)t * 64]));
    }
}

extern "C" void kernel_launch(void* const* d_in, const int* in_sizes, int n_in,
                              void* d_out, int out_size, void* d_ws, size_t ws_size,
                              hipStream_t stream) {
    const float* x  = (const float*)d_in[0];
    const float* e  = (const float*)d_in[1];
    const float* Wq = (const float*)d_in[2];
    const float* bq = (const float*)d_in[3];
    const float* Wk = (const float*)d_in[4];
    const float* bk = (const float*)d_in[5];
    const float* Wv = (const float*)d_in[6];
    const float* bv = (const float*)d_in[7];
    float* out = (float*)d_out;

    float* G  = (float*)d_ws;                        // [B*N, D]    512 KB
    float* V  = G + (size_t)Bc * Nc * Dc;            // [B*N, DH]   512 KB
    float* cc = V + (size_t)Bc * Nc * DHc;           // [B*N]       2 KB
    float* ai = cc + (size_t)Bc * Nc;                // [B*N*N]     512 KB

    float* eo = out + (size_t)Bc * Nc * Dc;

    prep_gvc<<<Bc * Nc / 4, 256, 0, stream>>>(x, Wq, bq, Wk, bk, Wv, bv,
                                              G, V, cc, out);
    score_pass<<<Bc * Nc * 16 / 4, 256, 0, stream>>>(e, G, cc, ai);
    combine_pass<<<Bc * Nc * 16 / 4, 256, 0, stream>>>(ai, V, eo);
}